// Round 6
// baseline (133.205 us; speedup 1.0000x reference)
//
#include <hip/hip_runtime.h>

// INRF, single self-contained kernel (no d_ws):
//   out[b,ij,c] = sum_pq [ M2[ij,pq]*x[b,pq,c] - W2[ij,pq]*relu(x[b,pq,c] - S[b,pq,ij,c]) ]
//   S[b,pq,ij,f] = sum_k patch(x)[b,pq,k] * G[ij,k,f],  K=144 (3x3x16) padded to 160.
// Per block (g -> 4 ij, b):
//   LDS union: gt[ij][k][f] bf16 (natural layout, conflict-free staging; k>=144 zeroed)
//              then reused as Xl = 35x34-cell halo bf16 image (XOR-swizzled 16B halves).
//   Bf built once into registers (160 one-time ds_read_u16); K-loop: 5 ds_read_b128
//   A-frags + 20 MFMA 16x16x32_bf16 + fp32 epilogue (W2/M2/x straight from global).
// B-side zero padding (gt rows k>=144) makes A-side pad values don't-care (finite junk*0).

typedef __attribute__((ext_vector_type(8))) short bf16x8;
typedef __attribute__((ext_vector_type(4))) float f32x4;

__device__ inline unsigned short f2bf(float x) {
    unsigned u = __float_as_uint(x);
    u += 0x7FFFu + ((u >> 16) & 1u);     // round-to-nearest-even
    return (unsigned short)(u >> 16);
}
__device__ inline unsigned pack2(float a, float b) {
    return (unsigned)f2bf(a) | ((unsigned)f2bf(b) << 16);
}

__global__ __launch_bounds__(256, 3) void inrf_fused(
    const float* __restrict__ inp,   // (4,1024,16)
    const float* __restrict__ M,     // 4096 per 4-ij group
    const float* __restrict__ Wp,    // 4096 per 4-ij group
    const float* __restrict__ G,     // 9216 per 4-ij group
    float* __restrict__ out)         // (4,1024,16)
{
    const int bid = blockIdx.x;
    const int g = bid >> 2, b = bid & 3;
    const int t = threadIdx.x, w = t >> 6, l = t & 63;
    const int quad = l >> 4, m = l & 15;      // m = A-row within tile = output col index
    const int half = quad & 1;

    // union: gt = short[4][160][16] (20480 B)  |  Xl = uint4[2380] (35x34 cells x 32B)
    __shared__ __align__(16) char uni[38080];
    __shared__ float red[4][64];
    uint4*    Xl  = (uint4*)uni;
    short*    gt  = (short*)uni;
    unsigned* gtw = (unsigned*)uni;

    // ---- 1. stage G -> gt bf16, k >= 144 zeroed (coalesced, conflict-free) ----
    {
        const float* Gs = G + g * 9216;
        for (int idx = t; idx < 5120; idx += 256) {      // one dword (2 bf16) per slot
            const int ij = idx / 1280;
            const int r = (idx - ij * 1280) * 2;         // k*16 + f
            unsigned v = 0;
            if (r < 2304) {
                const float2 s = *(const float2*)(Gs + ij * 2304 + r);
                v = pack2(s.x, s.y);
            }
            gtw[idx] = v;
        }
    }
    __syncthreads();

    // ---- 2. build B fragments into registers (one-time scalar LDS reads) ----
    bf16x8 Bf[4][5];
    {
        const int kq = quad * 8;
#pragma unroll
        for (int ij = 0; ij < 4; ++ij)
#pragma unroll
            for (int kk = 0; kk < 5; ++kk) {
                bf16x8 f;
                const short* s = gt + ij * 2560 + (kk * 32 + kq) * 16 + m;
#pragma unroll
                for (int j = 0; j < 8; ++j) f[j] = s[j * 16];
                Bf[ij][kk] = f;
            }
    }
    __syncthreads();                 // Bf reads done before Xl overwrites the union

    // ---- 3. zero Xl (incl. halo + fake row 34) ----
    for (int i = t; i < 2380; i += 256) Xl[i] = (uint4){0, 0, 0, 0};
    __syncthreads();                 // zeros visible before interior fill (race fix)

    // ---- 4. fill interior: image (p,q) -> halo cell (p+1, q+1), swizzled halves ----
    {
        const float4* xb = (const float4*)(inp + b * 16384);
        for (int r = t; r < 1024; r += 256) {
            const int p = r >> 5, q = r & 31;
            const int hc = (p + 1) * 34 + (q + 1);
            const float4 f0 = xb[r * 4 + 0], f1 = xb[r * 4 + 1];
            const float4 f2 = xb[r * 4 + 2], f3 = xb[r * 4 + 3];
            uint4 lo, hi;
            lo.x = pack2(f0.x, f0.y); lo.y = pack2(f0.z, f0.w);
            lo.z = pack2(f1.x, f1.y); lo.w = pack2(f1.z, f1.w);
            hi.x = pack2(f2.x, f2.y); hi.y = pack2(f2.z, f2.w);
            hi.z = pack2(f3.x, f3.y); hi.w = pack2(f3.z, f3.w);
            const int sw = hc & 1;
            Xl[2 * hc + sw] = lo;          // half 0
            Xl[2 * hc + (sw ^ 1)] = hi;    // half 1
        }
    }

    // per-lane A-frag offsets: frag kk covers k = kk*32 + quad*8 + j
    // tap = 2kk + (quad>>1) in 0..9 (tap 9 = pad: reads row<=34, finite, B=0)
    int K_[5];
#pragma unroll
    for (int kk = 0; kk < 5; ++kk) {
        const int tap = 2 * kk + (quad >> 1);
        const int dh = tap / 3, dw = tap - dh * 3;
        K_[kk] = (dh * 34 + dw) * 32 + ((half ^ (dw & 1)) << 4);
    }
    __syncthreads();

    const int tile0w = w * 16;                 // 16 M-tiles per wave
    const float* wrow = Wp + g * 4096;
    const float* mrow = M + g * 4096;
    const float* xrow = inp + b * 16384 + m;

    auto loadA = [&](int i, uint4* dst) {
        const int pq = (tile0w + i) * 16 + m;
        const int p = pq >> 5, q = pq & 31;
        const int base = (p * 34 + q) * 32;
        const int qo = (q & 1) << 4;
#pragma unroll
        for (int kk = 0; kk < 5; ++kk)
            dst[kk] = *(const uint4*)((const char*)Xl + ((base + K_[kk]) ^ qo));
    };

    float accv[4] = {0.f, 0.f, 0.f, 0.f};
    uint4 Acur[5], Anxt[5];
    loadA(0, Acur);

    for (int i = 0; i < 16; ++i) {
        const int pqb = (tile0w + i) * 16 + quad * 4;

        // issue W2/M2/x loads early; consumed after the MFMA block
        float4 w2[4], m2[4];
        float xv[4];
#pragma unroll
        for (int ij = 0; ij < 4; ++ij) {
            w2[ij] = *(const float4*)&wrow[ij * 1024 + pqb];
            m2[ij] = *(const float4*)&mrow[ij * 1024 + pqb];
        }
#pragma unroll
        for (int r = 0; r < 4; ++r) xv[r] = xrow[(pqb + r) * 16];

        if (i < 15) loadA(i + 1, Anxt);

        f32x4 C[4];
#pragma unroll
        for (int ij = 0; ij < 4; ++ij) C[ij] = (f32x4){0.f, 0.f, 0.f, 0.f};
#pragma unroll
        for (int kk = 0; kk < 5; ++kk) {
            const bf16x8 a = __builtin_bit_cast(bf16x8, Acur[kk]);
#pragma unroll
            for (int ij = 0; ij < 4; ++ij)
                C[ij] = __builtin_amdgcn_mfma_f32_16x16x32_bf16(a, Bf[ij][kk], C[ij], 0, 0, 0);
        }

        // fused epilogue: acc += M2*x - W2*relu(x - S);  C row r <-> pq = pqb + r, col = m
#pragma unroll
        for (int ij = 0; ij < 4; ++ij) {
            accv[ij] += m2[ij].x * xv[0] - w2[ij].x * fmaxf(xv[0] - C[ij][0], 0.f);
            accv[ij] += m2[ij].y * xv[1] - w2[ij].y * fmaxf(xv[1] - C[ij][1], 0.f);
            accv[ij] += m2[ij].z * xv[2] - w2[ij].z * fmaxf(xv[2] - C[ij][2], 0.f);
            accv[ij] += m2[ij].w * xv[3] - w2[ij].w * fmaxf(xv[3] - C[ij][3], 0.f);
        }

#pragma unroll
        for (int kk = 0; kk < 5; ++kk) Acur[kk] = Anxt[kk];
    }

    // reduce over quads; lanes 0..15 hold full column sums for this wave's tiles
#pragma unroll
    for (int ij = 0; ij < 4; ++ij) {
        float v = accv[ij];
        v += __shfl_xor(v, 16);
        v += __shfl_xor(v, 32);
        if (l < 16) red[w][ij * 16 + l] = v;
    }
    __syncthreads();

    if (t < 64) {
        const int oij = t >> 4, oc = t & 15;
        const float r0 = red[0][t] + red[1][t] + red[2][t] + red[3][t];
        out[b * 16384 + (g * 4 + oij) * 16 + oc] = r0;    // L = 1
    }
}

extern "C" void kernel_launch(void* const* d_in, const int* in_sizes, int n_in,
                              void* d_out, int out_size, void* d_ws, size_t ws_size,
                              hipStream_t stream) {
    const float* inp = (const float*)d_in[0];
    const float* M   = (const float*)d_in[1];
    const float* Wp  = (const float*)d_in[2];
    const float* G   = (const float*)d_in[3];
    float* out = (float*)d_out;

    inrf_fused<<<dim3(1024), dim3(256), 0, stream>>>(inp, M, Wp, G, out);
}